// Round 6
// baseline (387.613 us; speedup 1.0000x reference)
//
#include <hip/hip_runtime.h>

#define N_NODES 100000
#define DEG 16
#define DIM 128
#define NGROUPS 6250        // N_NODES / 16
#define GPB 2               // groups per dense block (flat, not pipelined)
#define DBLOCKS (NGROUPS / GPB)   // 3125

typedef short bf16x8 __attribute__((ext_vector_type(8)));
typedef float f32x4 __attribute__((ext_vector_type(4)));

__device__ __forceinline__ unsigned short f2bf(float f) {
    unsigned int u = __builtin_bit_cast(unsigned int, f);
    u = (u + 0x7fffu + ((u >> 16) & 1u)) >> 16;
    return (unsigned short)u;
}
__device__ __forceinline__ float bf2f(unsigned short h) {
    unsigned int u = ((unsigned int)h) << 16;
    return __builtin_bit_cast(float, u);
}
__device__ __forceinline__ bf16x8 pack_bf16x8(float4 lo, float4 hi) {
    bf16x8 f;
    f[0] = (short)f2bf(lo.x); f[1] = (short)f2bf(lo.y);
    f[2] = (short)f2bf(lo.z); f[3] = (short)f2bf(lo.w);
    f[4] = (short)f2bf(hi.x); f[5] = (short)f2bf(hi.y);
    f[6] = (short)f2bf(hi.z); f[7] = (short)f2bf(hi.w);
    return f;
}

// ---------------------------------------------------------------------------
// dense v6: zcat[n][0:128] = h @ W_W^T, zcat[n][128:256] = h @ W_U^T (bf16)
// + per-wave PARTIAL scores (waves 0,1) -> no barriers, no LDS.
// Flat structure: ALL global loads (h for both groups + full W slice) are
// issued as one batch before any dependent use -> ~48 x 16B in flight/lane.
// Operand-swapped MFMA: A = W rows (m = output col), B = h rows (n = node).
// C/D: node = lane&15, output col = wave*64 + ct*16 + quad*4 + reg.
// ---------------------------------------------------------------------------
template <bool F32IN>
__global__ __launch_bounds__(256, 2) void dense_fused(
    const void* __restrict__ hsrc,           // N x 128 (f32 or bf16)
    const float* __restrict__ W_W,           // 128 x 128 f32
    const float* __restrict__ W_U,           // 128 x 128 f32
    const float* __restrict__ W_a,           // 257 f32
    unsigned short* __restrict__ zcat,       // N x 256 bf16
    float* __restrict__ s_src0, float* __restrict__ s_src1,
    float* __restrict__ s_dst0, float* __restrict__ s_dst1)
{
    const int wave = threadIdx.x >> 6;
    const int lane = threadIdx.x & 63;
    const int n16 = lane & 15;
    const int quad = lane >> 4;
    const int gbase = blockIdx.x * GPB;

    // ---- issue h loads for both groups (batched) ----
    float4 hraw[GPB][8];                 // F32IN path
    bf16x8 hfrag[GPB][4];                // final fragments
#pragma unroll
    for (int g = 0; g < GPB; g++) {
        int nodebase = (gbase + g) * 16;
        if constexpr (F32IN) {
            const float* hrow = (const float*)hsrc + (size_t)(nodebase + n16) * DIM + quad * 8;
#pragma unroll
            for (int ks = 0; ks < 4; ks++) {
                hraw[g][ks * 2]     = *(const float4*)(hrow + ks * 32);
                hraw[g][ks * 2 + 1] = *(const float4*)(hrow + ks * 32 + 4);
            }
        } else {
            const unsigned short* hrow = (const unsigned short*)hsrc + (size_t)(nodebase + n16) * DIM + quad * 8;
#pragma unroll
            for (int ks = 0; ks < 4; ks++)
                hfrag[g][ks] = *(const bf16x8*)(hrow + ks * 32);
        }
    }

    // ---- load + convert W slice (raw loads batched per half) ----
    const float* Wbase = (wave < 2) ? (W_W + (size_t)wave * 64 * DIM)
                                    : (W_U + (size_t)(wave - 2) * 64 * DIM);
    bf16x8 wfrag[4][4];                  // [ct][ks]
#pragma unroll
    for (int half = 0; half < 2; half++) {
        float4 wraw[2][4][2];
#pragma unroll
        for (int c = 0; c < 2; c++) {
            int ct = half * 2 + c;
            const float* wrow = Wbase + (size_t)(ct * 16 + n16) * DIM + quad * 8;
#pragma unroll
            for (int ks = 0; ks < 4; ks++) {
                wraw[c][ks][0] = *(const float4*)(wrow + ks * 32);
                wraw[c][ks][1] = *(const float4*)(wrow + ks * 32 + 4);
            }
        }
#pragma unroll
        for (int c = 0; c < 2; c++)
#pragma unroll
            for (int ks = 0; ks < 4; ks++)
                wfrag[half * 2 + c][ks] = pack_bf16x8(wraw[c][ks][0], wraw[c][ks][1]);
    }

    // ---- convert h (f32 path) ----
    if constexpr (F32IN) {
#pragma unroll
        for (int g = 0; g < GPB; g++)
#pragma unroll
            for (int ks = 0; ks < 4; ks++)
                hfrag[g][ks] = pack_bf16x8(hraw[g][ks * 2], hraw[g][ks * 2 + 1]);
    }

    // ---- per-group: MFMA, store, scores ----
#pragma unroll
    for (int g = 0; g < GPB; g++) {
        const int nodebase = (gbase + g) * 16;

        f32x4 acc[4];
#pragma unroll
        for (int ct = 0; ct < 4; ct++) {
            f32x4 a = {0.f, 0.f, 0.f, 0.f};
#pragma unroll
            for (int ks = 0; ks < 4; ks++)
                a = __builtin_amdgcn_mfma_f32_16x16x32_bf16(wfrag[ct][ks], hfrag[g][ks], a, 0, 0, 0);
            acc[ct] = a;
        }

        unsigned short* orow = zcat + (size_t)(nodebase + n16) * 256 + wave * 64 + quad * 4;
#pragma unroll
        for (int ct = 0; ct < 4; ct++) {
            uint2 pk;
            pk.x = (unsigned int)f2bf(acc[ct][0]) | ((unsigned int)f2bf(acc[ct][1]) << 16);
            pk.y = (unsigned int)f2bf(acc[ct][2]) | ((unsigned int)f2bf(acc[ct][3]) << 16);
            *(uint2*)(orow + ct * 16) = pk;
        }

        if (wave < 2) {
            float ps = 0.f, pd = 0.f;
#pragma unroll
            for (int ct = 0; ct < 4; ct++) {
                float4 as = *(const float4*)(W_a + wave * 64 + ct * 16 + quad * 4);
                float4 ad = *(const float4*)(W_a + DIM + wave * 64 + ct * 16 + quad * 4);
                ps += acc[ct][0] * as.x + acc[ct][1] * as.y
                    + acc[ct][2] * as.z + acc[ct][3] * as.w;
                pd += acc[ct][0] * ad.x + acc[ct][1] * ad.y
                    + acc[ct][2] * ad.z + acc[ct][3] * ad.w;
            }
            ps += __shfl_xor(ps, 16); ps += __shfl_xor(ps, 32);
            pd += __shfl_xor(pd, 16); pd += __shfl_xor(pd, 32);
            if (lane < 16) {
                float* sp = wave == 0 ? s_src0 : s_src1;
                float* dp = wave == 0 ? s_dst0 : s_dst1;
                sp[nodebase + lane] = ps;
                dp[nodebase + lane] = pd;
            }
        }
    }
}

// ---------------------------------------------------------------------------
// aggr v4 (unchanged): 16 nodes/block, 256 threads.
// Phase 1: 1 thread/edge, 16-lane shfl softmax -> LDS.
// Phase 2: 16 threads/node, 8 cols each; all 16 uint4 gathers batched.
// ---------------------------------------------------------------------------
__global__ __launch_bounds__(256, 3) void aggr_kernel(
    const unsigned short* __restrict__ zcat,
    const float* __restrict__ s_src0, const float* __restrict__ s_src1,
    const float* __restrict__ s_dst0, const float* __restrict__ s_dst1,
    const float* __restrict__ edge_d,
    const int* __restrict__ edge_src,
    const float* __restrict__ W_V,          // 1 float
    const float* __restrict__ W_a,          // a_t = W_a[256]
    unsigned short* __restrict__ out_bf16,  // layer-1 target (or null)
    float* __restrict__ out_f32)            // layer-2 target (or null)
{
    __shared__ float alpha_s[16][DEG];
    __shared__ int   src_s[16][DEG];

    const int t = threadIdx.x;
    const int base = blockIdx.x * 16;

    {
        int nl = t >> 4, j = t & 15;
        int node = base + nl;
        int e = node * DEG + j;
        int s = edge_src[e];
        float coef = W_V[0] * W_a[2 * DIM];
        float x = (s_src0[s] + s_src1[s]) + (s_dst0[node] + s_dst1[node])
                + edge_d[e] * coef;
        x = x > 0.f ? x : 0.01f * x;
        float m = x;
        m = fmaxf(m, __shfl_xor(m, 1));
        m = fmaxf(m, __shfl_xor(m, 2));
        m = fmaxf(m, __shfl_xor(m, 4));
        m = fmaxf(m, __shfl_xor(m, 8));
        float ex = __expf(x - m);
        float d = ex;
        d += __shfl_xor(d, 1); d += __shfl_xor(d, 2);
        d += __shfl_xor(d, 4); d += __shfl_xor(d, 8);
        alpha_s[nl][j] = ex / d;
        src_s[nl][j] = s;
    }
    __syncthreads();

    const int nl = t >> 4;
    const int node = base + nl;
    const int c8 = (t & 15) * 8;

    uint4 raw[DEG];
#pragma unroll
    for (int j = 0; j < DEG; j++)
        raw[j] = *(const uint4*)(zcat + (size_t)src_s[nl][j] * 256 + c8);
    uint4 zr = *(const uint4*)(zcat + (size_t)node * 256 + 128 + c8);

    float acc[8] = {};
#pragma unroll
    for (int j = 0; j < DEG; j++) {
        float a = alpha_s[nl][j];
        acc[0] += a * bf2f((unsigned short)raw[j].x);
        acc[1] += a * bf2f((unsigned short)(raw[j].x >> 16));
        acc[2] += a * bf2f((unsigned short)raw[j].y);
        acc[3] += a * bf2f((unsigned short)(raw[j].y >> 16));
        acc[4] += a * bf2f((unsigned short)raw[j].z);
        acc[5] += a * bf2f((unsigned short)(raw[j].z >> 16));
        acc[6] += a * bf2f((unsigned short)raw[j].w);
        acc[7] += a * bf2f((unsigned short)(raw[j].w >> 16));
    }

    float v[8];
    v[0] = fmaxf(bf2f((unsigned short)zr.x) + acc[0], 0.f);
    v[1] = fmaxf(bf2f((unsigned short)(zr.x >> 16)) + acc[1], 0.f);
    v[2] = fmaxf(bf2f((unsigned short)zr.y) + acc[2], 0.f);
    v[3] = fmaxf(bf2f((unsigned short)(zr.y >> 16)) + acc[3], 0.f);
    v[4] = fmaxf(bf2f((unsigned short)zr.z) + acc[4], 0.f);
    v[5] = fmaxf(bf2f((unsigned short)(zr.z >> 16)) + acc[5], 0.f);
    v[6] = fmaxf(bf2f((unsigned short)zr.w) + acc[6], 0.f);
    v[7] = fmaxf(bf2f((unsigned short)(zr.w >> 16)) + acc[7], 0.f);

    if (out_f32) {
        float* op = out_f32 + (size_t)node * DIM + c8;
        *(float4*)op       = make_float4(v[0], v[1], v[2], v[3]);
        *(float4*)(op + 4) = make_float4(v[4], v[5], v[6], v[7]);
    } else {
        uint4 pk;
        pk.x = (unsigned int)f2bf(v[0]) | ((unsigned int)f2bf(v[1]) << 16);
        pk.y = (unsigned int)f2bf(v[2]) | ((unsigned int)f2bf(v[3]) << 16);
        pk.z = (unsigned int)f2bf(v[4]) | ((unsigned int)f2bf(v[5]) << 16);
        pk.w = (unsigned int)f2bf(v[6]) | ((unsigned int)f2bf(v[7]) << 16);
        *(uint4*)(out_bf16 + (size_t)node * DIM + c8) = pk;
    }
}

// ---------------------------------------------------------------------------
extern "C" void kernel_launch(void* const* d_in, const int* in_sizes, int n_in,
                              void* d_out, int out_size, void* d_ws, size_t ws_size,
                              hipStream_t stream) {
    const float* attr     = (const float*)d_in[0];
    const float* edge_d   = (const float*)d_in[1];
    const float* W_V1     = (const float*)d_in[2];
    const float* W_W1     = (const float*)d_in[3];
    const float* W_U1     = (const float*)d_in[4];
    const float* W_a1     = (const float*)d_in[5];
    const float* W_V2     = (const float*)d_in[6];
    const float* W_W2     = (const float*)d_in[7];
    const float* W_U2     = (const float*)d_in[8];
    const float* W_a2     = (const float*)d_in[9];
    const int*   edge_src = (const int*)d_in[10];

    float* out = (float*)d_out;

    char* ws = (char*)d_ws;
    unsigned short* zcat = (unsigned short*)ws;                        // 51.2 MB
    unsigned short* h1   = (unsigned short*)(ws + 52u * 1024 * 1024);  // 25.6 MB
    float* s_src0        = (float*)(ws + 78u * 1024 * 1024);
    float* s_src1        = (float*)(ws + 79u * 1024 * 1024);
    float* s_dst0        = (float*)(ws + 80u * 1024 * 1024);
    float* s_dst1        = (float*)(ws + 81u * 1024 * 1024);

    // ---- layer 1 ----
    dense_fused<true><<<DBLOCKS, 256, 0, stream>>>(attr, W_W1, W_U1, W_a1, zcat,
                                                   s_src0, s_src1, s_dst0, s_dst1);
    aggr_kernel<<<NGROUPS, 256, 0, stream>>>(zcat, s_src0, s_src1, s_dst0, s_dst1,
                                             edge_d, edge_src, W_V1, W_a1, h1, nullptr);

    // ---- layer 2 ----
    dense_fused<false><<<DBLOCKS, 256, 0, stream>>>(h1, W_W2, W_U2, W_a2, zcat,
                                                    s_src0, s_src1, s_dst0, s_dst1);
    aggr_kernel<<<NGROUPS, 256, 0, stream>>>(zcat, s_src0, s_src1, s_dst0, s_dst1,
                                             edge_d, edge_src, W_V2, W_a2, nullptr, out);
}

// Round 7
// 350.030 us; speedup vs baseline: 1.1074x; 1.1074x over previous
//
#include <hip/hip_runtime.h>

#define N_NODES 100000
#define DEG 16
#define DIM 128
#define NTILES 1563          // ceil(100000/64)
#define LSTR 136             // LDS row stride in shorts (128 + 8 pad, 16B-aligned)

typedef short bf16x8 __attribute__((ext_vector_type(8)));
typedef float f32x4 __attribute__((ext_vector_type(4)));

__device__ __forceinline__ unsigned short f2bf(float f) {
    unsigned int u = __builtin_bit_cast(unsigned int, f);
    u = (u + 0x7fffu + ((u >> 16) & 1u)) >> 16;
    return (unsigned short)u;
}
__device__ __forceinline__ float bf2f(unsigned short h) {
    unsigned int u = ((unsigned int)h) << 16;
    return __builtin_bit_cast(float, u);
}
__device__ __forceinline__ bf16x8 pack_bf16x8(float4 lo, float4 hi) {
    bf16x8 f;
    f[0] = (short)f2bf(lo.x); f[1] = (short)f2bf(lo.y);
    f[2] = (short)f2bf(lo.z); f[3] = (short)f2bf(lo.w);
    f[4] = (short)f2bf(hi.x); f[5] = (short)f2bf(hi.y);
    f[6] = (short)f2bf(hi.z); f[7] = (short)f2bf(hi.w);
    return f;
}

// ---------------------------------------------------------------------------
// dense v7: LDS-staged tile GEMM. Block = 64 nodes x 64 output cols.
// grid = (4, 1563): blockIdx.x = col-block cb (0,1 -> z cols 0-63/64-127;
// 2,3 -> zi), blockIdx.y = node tile. Stage W-slice + h-tile to LDS (bf16),
// barrier, each wave computes 16 nodes x 64 cols via 16 MFMAs.
// Scores fused: cb=0 -> s_src0/s_dst0 partials, cb=1 -> s_src1/s_dst1.
// ---------------------------------------------------------------------------
template <bool F32IN>
__global__ __launch_bounds__(256, 4) void dense_tile(
    const void* __restrict__ hsrc,           // N x 128 (f32 or bf16)
    const float* __restrict__ W_W,           // 128 x 128 f32
    const float* __restrict__ W_U,           // 128 x 128 f32
    const float* __restrict__ W_a,           // 257 f32
    unsigned short* __restrict__ z,          // N x 128 bf16
    unsigned short* __restrict__ zi,         // N x 128 bf16
    float* __restrict__ s_src0, float* __restrict__ s_src1,
    float* __restrict__ s_dst0, float* __restrict__ s_dst1)
{
    __shared__ unsigned short Wt[64 * LSTR];
    __shared__ unsigned short Ht[64 * LSTR];

    const int cb = blockIdx.x;               // 0..3
    const int nodebase = blockIdx.y * 64;
    const int t = threadIdx.x;

    // ---- stage W slice: 64 rows x 128 cols fp32 -> bf16 LDS ----
    {
        const float* Wsrc = (cb < 2 ? W_W : W_U) + (size_t)(cb & 1) * 64 * DIM;
        int r = t >> 2, c0 = (t & 3) * 32;
        const float* src = Wsrc + (size_t)r * DIM + c0;
        float4 v[8];
#pragma unroll
        for (int i = 0; i < 8; i++) v[i] = *(const float4*)(src + i * 4);
        unsigned short* dst = Wt + r * LSTR + c0;
#pragma unroll
        for (int i = 0; i < 4; i++)
            *(bf16x8*)(dst + i * 8) = pack_bf16x8(v[2 * i], v[2 * i + 1]);
    }
    // ---- stage h tile: 64 nodes x 128 cols -> bf16 LDS ----
    {
        int r = t >> 2, c0 = (t & 3) * 32;
        int node = nodebase + r;
        unsigned short* dst = Ht + r * LSTR + c0;
        if (F32IN) {
            float4 v[8];
#pragma unroll
            for (int i = 0; i < 8; i++) v[i] = make_float4(0.f, 0.f, 0.f, 0.f);
            if (node < N_NODES) {
                const float* src = (const float*)hsrc + (size_t)node * DIM + c0;
#pragma unroll
                for (int i = 0; i < 8; i++) v[i] = *(const float4*)(src + i * 4);
            }
#pragma unroll
            for (int i = 0; i < 4; i++)
                *(bf16x8*)(dst + i * 8) = pack_bf16x8(v[2 * i], v[2 * i + 1]);
        } else {
            uint4 u[4];
#pragma unroll
            for (int i = 0; i < 4; i++) u[i] = make_uint4(0, 0, 0, 0);
            if (node < N_NODES) {
                const unsigned short* src = (const unsigned short*)hsrc + (size_t)node * DIM + c0;
#pragma unroll
                for (int i = 0; i < 4; i++) u[i] = *(const uint4*)(src + i * 8);
            }
#pragma unroll
            for (int i = 0; i < 4; i++) *(uint4*)(dst + i * 8) = u[i];
        }
    }
    __syncthreads();

    // ---- compute: wave w handles nodes [w*16, w*16+16) x 64 cols ----
    const int wave = t >> 6;
    const int lane = t & 63;
    const int n16 = lane & 15;
    const int quad = lane >> 4;
    const int node = nodebase + wave * 16 + n16;

    bf16x8 hfrag[4];
    const unsigned short* hrow = Ht + (wave * 16 + n16) * LSTR + quad * 8;
#pragma unroll
    for (int ks = 0; ks < 4; ks++)
        hfrag[ks] = *(const bf16x8*)(hrow + ks * 32);

    f32x4 acc[4];
#pragma unroll
    for (int ct = 0; ct < 4; ct++) {
        const unsigned short* wrow = Wt + (ct * 16 + n16) * LSTR + quad * 8;
        f32x4 a = {0.f, 0.f, 0.f, 0.f};
#pragma unroll
        for (int ks = 0; ks < 4; ks++)
            a = __builtin_amdgcn_mfma_f32_16x16x32_bf16(
                    *(const bf16x8*)(wrow + ks * 32), hfrag[ks], a, 0, 0, 0);
        acc[ct] = a;
    }

    // ---- store: 4 packed uint2 per lane ----
    if (node < N_NODES) {
        unsigned short* zout = (cb < 2 ? z : zi);
        unsigned short* orow = zout + (size_t)node * DIM + (cb & 1) * 64 + quad * 4;
#pragma unroll
        for (int ct = 0; ct < 4; ct++) {
            uint2 pk;
            pk.x = (unsigned int)f2bf(acc[ct][0]) | ((unsigned int)f2bf(acc[ct][1]) << 16);
            pk.y = (unsigned int)f2bf(acc[ct][2]) | ((unsigned int)f2bf(acc[ct][3]) << 16);
            *(uint2*)(orow + ct * 16) = pk;
        }
    }

    // ---- fused score partials (z col-blocks only) ----
    if (cb < 2) {
        float ps = 0.f, pd = 0.f;
#pragma unroll
        for (int ct = 0; ct < 4; ct++) {
            float4 as = *(const float4*)(W_a + cb * 64 + ct * 16 + quad * 4);
            float4 ad = *(const float4*)(W_a + DIM + cb * 64 + ct * 16 + quad * 4);
            ps += acc[ct][0] * as.x + acc[ct][1] * as.y
                + acc[ct][2] * as.z + acc[ct][3] * as.w;
            pd += acc[ct][0] * ad.x + acc[ct][1] * ad.y
                + acc[ct][2] * ad.z + acc[ct][3] * ad.w;
        }
        ps += __shfl_xor(ps, 16); ps += __shfl_xor(ps, 32);
        pd += __shfl_xor(pd, 16); pd += __shfl_xor(pd, 32);
        if (lane < 16 && node < N_NODES) {
            (cb == 0 ? s_src0 : s_src1)[node] = ps;
            (cb == 0 ? s_dst0 : s_dst1)[node] = pd;
        }
    }
}

// ---------------------------------------------------------------------------
// aggr v5: 16 nodes/block, 256 threads. z and zi are now SEPARATE arrays
// (gather footprint 25.6 MB -> better L2/L3 residency).
// Phase 1: 1 thread/edge, 16-lane shfl softmax -> LDS.
// Phase 2: 16 threads/node, 8 cols each; all 16 uint4 gathers batched.
// ---------------------------------------------------------------------------
__global__ __launch_bounds__(256, 3) void aggr_kernel(
    const unsigned short* __restrict__ z,    // N x 128 bf16
    const unsigned short* __restrict__ zi,   // N x 128 bf16
    const float* __restrict__ s_src0, const float* __restrict__ s_src1,
    const float* __restrict__ s_dst0, const float* __restrict__ s_dst1,
    const float* __restrict__ edge_d,
    const int* __restrict__ edge_src,
    const float* __restrict__ W_V,           // 1 float
    const float* __restrict__ W_a,           // a_t = W_a[256]
    unsigned short* __restrict__ out_bf16,   // layer-1 target (or null)
    float* __restrict__ out_f32)             // layer-2 target (or null)
{
    __shared__ float alpha_s[16][DEG];
    __shared__ int   src_s[16][DEG];

    const int t = threadIdx.x;
    const int base = blockIdx.x * 16;

    {
        int nl = t >> 4, j = t & 15;
        int node = base + nl;
        int e = node * DEG + j;
        int s = edge_src[e];
        float coef = W_V[0] * W_a[2 * DIM];
        float x = (s_src0[s] + s_src1[s]) + (s_dst0[node] + s_dst1[node])
                + edge_d[e] * coef;
        x = x > 0.f ? x : 0.01f * x;
        float m = x;
        m = fmaxf(m, __shfl_xor(m, 1));
        m = fmaxf(m, __shfl_xor(m, 2));
        m = fmaxf(m, __shfl_xor(m, 4));
        m = fmaxf(m, __shfl_xor(m, 8));
        float ex = __expf(x - m);
        float d = ex;
        d += __shfl_xor(d, 1); d += __shfl_xor(d, 2);
        d += __shfl_xor(d, 4); d += __shfl_xor(d, 8);
        alpha_s[nl][j] = ex / d;
        src_s[nl][j] = s;
    }
    __syncthreads();

    const int nl = t >> 4;
    const int node = base + nl;
    const int c8 = (t & 15) * 8;

    uint4 raw[DEG];
#pragma unroll
    for (int j = 0; j < DEG; j++)
        raw[j] = *(const uint4*)(z + (size_t)src_s[nl][j] * DIM + c8);
    uint4 zr = *(const uint4*)(zi + (size_t)node * DIM + c8);

    float acc[8] = {};
#pragma unroll
    for (int j = 0; j < DEG; j++) {
        float a = alpha_s[nl][j];
        acc[0] += a * bf2f((unsigned short)raw[j].x);
        acc[1] += a * bf2f((unsigned short)(raw[j].x >> 16));
        acc[2] += a * bf2f((unsigned short)raw[j].y);
        acc[3] += a * bf2f((unsigned short)(raw[j].y >> 16));
        acc[4] += a * bf2f((unsigned short)raw[j].z);
        acc[5] += a * bf2f((unsigned short)(raw[j].z >> 16));
        acc[6] += a * bf2f((unsigned short)raw[j].w);
        acc[7] += a * bf2f((unsigned short)(raw[j].w >> 16));
    }

    float v[8];
    v[0] = fmaxf(bf2f((unsigned short)zr.x) + acc[0], 0.f);
    v[1] = fmaxf(bf2f((unsigned short)(zr.x >> 16)) + acc[1], 0.f);
    v[2] = fmaxf(bf2f((unsigned short)zr.y) + acc[2], 0.f);
    v[3] = fmaxf(bf2f((unsigned short)(zr.y >> 16)) + acc[3], 0.f);
    v[4] = fmaxf(bf2f((unsigned short)zr.z) + acc[4], 0.f);
    v[5] = fmaxf(bf2f((unsigned short)(zr.z >> 16)) + acc[5], 0.f);
    v[6] = fmaxf(bf2f((unsigned short)zr.w) + acc[6], 0.f);
    v[7] = fmaxf(bf2f((unsigned short)(zr.w >> 16)) + acc[7], 0.f);

    if (out_f32) {
        float* op = out_f32 + (size_t)node * DIM + c8;
        *(float4*)op       = make_float4(v[0], v[1], v[2], v[3]);
        *(float4*)(op + 4) = make_float4(v[4], v[5], v[6], v[7]);
    } else {
        uint4 pk;
        pk.x = (unsigned int)f2bf(v[0]) | ((unsigned int)f2bf(v[1]) << 16);
        pk.y = (unsigned int)f2bf(v[2]) | ((unsigned int)f2bf(v[3]) << 16);
        pk.z = (unsigned int)f2bf(v[4]) | ((unsigned int)f2bf(v[5]) << 16);
        pk.w = (unsigned int)f2bf(v[6]) | ((unsigned int)f2bf(v[7]) << 16);
        *(uint4*)(out_bf16 + (size_t)node * DIM + c8) = pk;
    }
}

// ---------------------------------------------------------------------------
extern "C" void kernel_launch(void* const* d_in, const int* in_sizes, int n_in,
                              void* d_out, int out_size, void* d_ws, size_t ws_size,
                              hipStream_t stream) {
    const float* attr     = (const float*)d_in[0];
    const float* edge_d   = (const float*)d_in[1];
    const float* W_V1     = (const float*)d_in[2];
    const float* W_W1     = (const float*)d_in[3];
    const float* W_U1     = (const float*)d_in[4];
    const float* W_a1     = (const float*)d_in[5];
    const float* W_V2     = (const float*)d_in[6];
    const float* W_W2     = (const float*)d_in[7];
    const float* W_U2     = (const float*)d_in[8];
    const float* W_a2     = (const float*)d_in[9];
    const int*   edge_src = (const int*)d_in[10];

    float* out = (float*)d_out;

    char* ws = (char*)d_ws;
    unsigned short* z    = (unsigned short*)ws;                        // 25.6 MB
    unsigned short* zi   = (unsigned short*)(ws + 26u * 1024 * 1024);  // 25.6 MB
    unsigned short* h1   = (unsigned short*)(ws + 52u * 1024 * 1024);  // 25.6 MB
    float* s_src0        = (float*)(ws + 78u * 1024 * 1024);
    float* s_src1        = (float*)(ws + 79u * 1024 * 1024);
    float* s_dst0        = (float*)(ws + 80u * 1024 * 1024);
    float* s_dst1        = (float*)(ws + 81u * 1024 * 1024);

    dim3 dgrid(4, NTILES);

    // ---- layer 1 ----
    dense_tile<true><<<dgrid, 256, 0, stream>>>(attr, W_W1, W_U1, W_a1, z, zi,
                                                s_src0, s_src1, s_dst0, s_dst1);
    aggr_kernel<<<6250, 256, 0, stream>>>(z, zi, s_src0, s_src1, s_dst0, s_dst1,
                                          edge_d, edge_src, W_V1, W_a1, h1, nullptr);

    // ---- layer 2 ----
    dense_tile<false><<<dgrid, 256, 0, stream>>>(h1, W_W2, W_U2, W_a2, z, zi,
                                                 s_src0, s_src1, s_dst0, s_dst1);
    aggr_kernel<<<6250, 256, 0, stream>>>(z, zi, s_src0, s_src1, s_dst0, s_dst1,
                                          edge_d, edge_src, W_V2, W_a2, nullptr, out);
}

// Round 8
// 326.160 us; speedup vs baseline: 1.1884x; 1.0732x over previous
//
#include <hip/hip_runtime.h>

#define N_NODES 100000
#define DEG 16
#define DIM 128
#define NTILES 1563          // ceil(100000/64)
#define T8 196               // ceil(NTILES/8)
#define DGRID (T8 * 4 * 8)   // 6272 (some inert)
#define LSTR 136             // LDS row stride in shorts (16B-aligned, conflict-light)

typedef short bf16x8 __attribute__((ext_vector_type(8)));
typedef float f32x4 __attribute__((ext_vector_type(4)));

__device__ __forceinline__ unsigned short f2bf(float f) {
    unsigned int u = __builtin_bit_cast(unsigned int, f);
    u = (u + 0x7fffu + ((u >> 16) & 1u)) >> 16;
    return (unsigned short)u;
}
__device__ __forceinline__ float bf2f(unsigned short h) {
    unsigned int u = ((unsigned int)h) << 16;
    return __builtin_bit_cast(float, u);
}
__device__ __forceinline__ bf16x8 pack_bf16x8(float4 lo, float4 hi) {
    bf16x8 f;
    f[0] = (short)f2bf(lo.x); f[1] = (short)f2bf(lo.y);
    f[2] = (short)f2bf(lo.z); f[3] = (short)f2bf(lo.w);
    f[4] = (short)f2bf(hi.x); f[5] = (short)f2bf(hi.y);
    f[6] = (short)f2bf(hi.z); f[7] = (short)f2bf(hi.w);
    return f;
}

// ---------------------------------------------------------------------------
// prep: cast W_W1|W_U1 -> Wc1 (256x128 bf16), W_W2|W_U2 -> Wc2
// ---------------------------------------------------------------------------
__global__ __launch_bounds__(256) void prep_w(
    const float* __restrict__ W_W1, const float* __restrict__ W_U1,
    const float* __restrict__ W_W2, const float* __restrict__ W_U2,
    unsigned short* __restrict__ Wc1, unsigned short* __restrict__ Wc2)
{
    int idx = blockIdx.x * 256 + threadIdx.x;      // 0..65535
    int half = idx & 32767;
    const float* src = (idx < 32768)
        ? (half < 16384 ? W_W1 + half : W_U1 + half - 16384)
        : (half < 16384 ? W_W2 + half : W_U2 + half - 16384);
    unsigned short* dst = (idx < 32768) ? Wc1 + half : Wc2 + half;
    *dst = f2bf(*src);
}

// ---------------------------------------------------------------------------
// dense1: z1 = attr @ W_W1^T, zi1 = attr @ W_U1^T (bf16) + score partials.
// Block = 64 nodes x 64 output cols. 1-D grid, XCD-swizzled so the 4
// col-blocks of one tile land on the SAME XCD (h fetched once per tile).
// ---------------------------------------------------------------------------
__global__ __launch_bounds__(256, 4) void dense_tile(
    const float* __restrict__ hsrc,          // N x 128 f32 (attr)
    const unsigned short* __restrict__ Wc,   // 256 x 128 bf16 (W_W1|W_U1)
    const float* __restrict__ W_a,           // 257 f32
    unsigned short* __restrict__ z,          // N x 128 bf16
    unsigned short* __restrict__ zi,         // N x 128 bf16
    float* __restrict__ s_src0, float* __restrict__ s_src1,
    float* __restrict__ s_dst0, float* __restrict__ s_dst1)
{
    __shared__ unsigned short Wt[64 * LSTR];
    __shared__ unsigned short Ht[64 * LSTR];

    // swizzle: same-XCD consecutive blocks = 4 col-blocks of one tile
    const int bid = blockIdx.x;
    const int xcd = bid & 7;
    const int q = bid >> 3;
    const int cb = q & 3;                    // col-block 0..3
    const int tile = (q >> 2) * 8 + xcd;
    if (tile >= NTILES) return;
    const int nodebase = tile * 64;
    const int t = threadIdx.x;

    // ---- stage W slice (bf16, plain copies) ----
    {
        int r = t >> 2, c0 = (t & 3) * 32;
        const unsigned short* src = Wc + (size_t)(cb * 64 + r) * DIM + c0;
        unsigned short* dst = Wt + r * LSTR + c0;
#pragma unroll
        for (int i = 0; i < 4; i++)
            *(uint4*)(dst + i * 8) = *(const uint4*)(src + i * 8);
    }
    // ---- stage h tile: 64 nodes x 128 f32 -> bf16 ----
    {
        int r = t >> 2, c0 = (t & 3) * 32;
        int node = nodebase + r;
        unsigned short* dst = Ht + r * LSTR + c0;
        float4 v[8];
#pragma unroll
        for (int i = 0; i < 8; i++) v[i] = make_float4(0.f, 0.f, 0.f, 0.f);
        if (node < N_NODES) {
            const float* src = hsrc + (size_t)node * DIM + c0;
#pragma unroll
            for (int i = 0; i < 8; i++) v[i] = *(const float4*)(src + i * 4);
        }
#pragma unroll
        for (int i = 0; i < 4; i++)
            *(bf16x8*)(dst + i * 8) = pack_bf16x8(v[2 * i], v[2 * i + 1]);
    }
    __syncthreads();

    const int wave = t >> 6;
    const int lane = t & 63;
    const int n16 = lane & 15;
    const int quad = lane >> 4;
    const int node = nodebase + wave * 16 + n16;

    bf16x8 hfrag[4];
    const unsigned short* hrow = Ht + (wave * 16 + n16) * LSTR + quad * 8;
#pragma unroll
    for (int ks = 0; ks < 4; ks++)
        hfrag[ks] = *(const bf16x8*)(hrow + ks * 32);

    f32x4 acc[4];
#pragma unroll
    for (int ct = 0; ct < 4; ct++) {
        const unsigned short* wrow = Wt + (ct * 16 + n16) * LSTR + quad * 8;
        f32x4 a = {0.f, 0.f, 0.f, 0.f};
#pragma unroll
        for (int ks = 0; ks < 4; ks++)
            a = __builtin_amdgcn_mfma_f32_16x16x32_bf16(
                    *(const bf16x8*)(wrow + ks * 32), hfrag[ks], a, 0, 0, 0);
        acc[ct] = a;
    }

    if (node < N_NODES) {
        unsigned short* zout = (cb < 2 ? z : zi);
        unsigned short* orow = zout + (size_t)node * DIM + (cb & 1) * 64 + quad * 4;
#pragma unroll
        for (int ct = 0; ct < 4; ct++) {
            uint2 pk;
            pk.x = (unsigned int)f2bf(acc[ct][0]) | ((unsigned int)f2bf(acc[ct][1]) << 16);
            pk.y = (unsigned int)f2bf(acc[ct][2]) | ((unsigned int)f2bf(acc[ct][3]) << 16);
            *(uint2*)(orow + ct * 16) = pk;
        }
    }

    if (cb < 2) {
        float ps = 0.f, pd = 0.f;
#pragma unroll
        for (int ct = 0; ct < 4; ct++) {
            float4 as = *(const float4*)(W_a + cb * 64 + ct * 16 + quad * 4);
            float4 ad = *(const float4*)(W_a + DIM + cb * 64 + ct * 16 + quad * 4);
            ps += acc[ct][0] * as.x + acc[ct][1] * as.y
                + acc[ct][2] * as.z + acc[ct][3] * as.w;
            pd += acc[ct][0] * ad.x + acc[ct][1] * ad.y
                + acc[ct][2] * ad.z + acc[ct][3] * ad.w;
        }
        ps += __shfl_xor(ps, 16); ps += __shfl_xor(ps, 32);
        pd += __shfl_xor(pd, 16); pd += __shfl_xor(pd, 32);
        if (lane < 16 && node < N_NODES) {
            (cb == 0 ? s_src0 : s_src1)[node] = ps;
            (cb == 0 ? s_dst0 : s_dst1)[node] = pd;
        }
    }
}

// ---------------------------------------------------------------------------
// aggr_dense: 16 nodes/block. Does layer-1 softmax-aggregate (h1 -> LDS only)
// then layer-2 dense (z2/zi2 = h1 @ W2^T) + layer-2 score partials.
// h1 never touches HBM; the entire layer-2 dense dispatch is eliminated.
// ---------------------------------------------------------------------------
__global__ __launch_bounds__(256, 3) void aggr_dense(
    const unsigned short* __restrict__ z,    // z1
    const unsigned short* __restrict__ zi,   // zi1
    const float* __restrict__ s_src0, const float* __restrict__ s_src1,
    const float* __restrict__ s_dst0, const float* __restrict__ s_dst1,
    const float* __restrict__ edge_d,
    const int* __restrict__ edge_src,
    const float* __restrict__ W_V,           // W_V1 (1 float)
    const float* __restrict__ W_a,           // W_a1 (a_t = [256])
    const unsigned short* __restrict__ Wc2,  // 256 x 128 bf16 (W_W2|W_U2)
    const float* __restrict__ W_a2,          // 257 f32 (layer-2 scores)
    unsigned short* __restrict__ z2,
    unsigned short* __restrict__ zi2,
    float* __restrict__ t_src0, float* __restrict__ t_src1,
    float* __restrict__ t_dst0, float* __restrict__ t_dst1)
{
    __shared__ float alpha_s[16][DEG];
    __shared__ int   src_s[16][DEG];
    __shared__ unsigned short Hl[16 * LSTR];

    const int t = threadIdx.x;
    const int base = blockIdx.x * 16;

    // ---- phase 1: softmax over each node's 16 edges ----
    {
        int nl = t >> 4, j = t & 15;
        int node = base + nl;
        int e = node * DEG + j;
        int s = edge_src[e];
        float coef = W_V[0] * W_a[2 * DIM];
        float x = (s_src0[s] + s_src1[s]) + (s_dst0[node] + s_dst1[node])
                + edge_d[e] * coef;
        x = x > 0.f ? x : 0.01f * x;
        float m = x;
        m = fmaxf(m, __shfl_xor(m, 1));
        m = fmaxf(m, __shfl_xor(m, 2));
        m = fmaxf(m, __shfl_xor(m, 4));
        m = fmaxf(m, __shfl_xor(m, 8));
        float ex = __expf(x - m);
        float d = ex;
        d += __shfl_xor(d, 1); d += __shfl_xor(d, 2);
        d += __shfl_xor(d, 4); d += __shfl_xor(d, 8);
        alpha_s[nl][j] = ex / d;
        src_s[nl][j] = s;
    }
    __syncthreads();

    // ---- phase 2: gather-aggregate; h1 row -> LDS (bf16) ----
    {
        const int nl = t >> 4;
        const int node = base + nl;
        const int c8 = (t & 15) * 8;

        uint4 raw[DEG];
#pragma unroll
        for (int j = 0; j < DEG; j++)
            raw[j] = *(const uint4*)(z + (size_t)src_s[nl][j] * DIM + c8);
        uint4 zr = *(const uint4*)(zi + (size_t)node * DIM + c8);

        float acc[8] = {};
#pragma unroll
        for (int j = 0; j < DEG; j++) {
            float a = alpha_s[nl][j];
            acc[0] += a * bf2f((unsigned short)raw[j].x);
            acc[1] += a * bf2f((unsigned short)(raw[j].x >> 16));
            acc[2] += a * bf2f((unsigned short)raw[j].y);
            acc[3] += a * bf2f((unsigned short)(raw[j].y >> 16));
            acc[4] += a * bf2f((unsigned short)raw[j].z);
            acc[5] += a * bf2f((unsigned short)(raw[j].z >> 16));
            acc[6] += a * bf2f((unsigned short)raw[j].w);
            acc[7] += a * bf2f((unsigned short)(raw[j].w >> 16));
        }

        float v[8];
        v[0] = fmaxf(bf2f((unsigned short)zr.x) + acc[0], 0.f);
        v[1] = fmaxf(bf2f((unsigned short)(zr.x >> 16)) + acc[1], 0.f);
        v[2] = fmaxf(bf2f((unsigned short)zr.y) + acc[2], 0.f);
        v[3] = fmaxf(bf2f((unsigned short)(zr.y >> 16)) + acc[3], 0.f);
        v[4] = fmaxf(bf2f((unsigned short)zr.z) + acc[4], 0.f);
        v[5] = fmaxf(bf2f((unsigned short)(zr.z >> 16)) + acc[5], 0.f);
        v[6] = fmaxf(bf2f((unsigned short)zr.w) + acc[6], 0.f);
        v[7] = fmaxf(bf2f((unsigned short)(zr.w >> 16)) + acc[7], 0.f);

        uint4 pk;
        pk.x = (unsigned int)f2bf(v[0]) | ((unsigned int)f2bf(v[1]) << 16);
        pk.y = (unsigned int)f2bf(v[2]) | ((unsigned int)f2bf(v[3]) << 16);
        pk.z = (unsigned int)f2bf(v[4]) | ((unsigned int)f2bf(v[5]) << 16);
        pk.w = (unsigned int)f2bf(v[6]) | ((unsigned int)f2bf(v[7]) << 16);
        *(uint4*)(Hl + nl * LSTR + c8) = pk;
    }
    __syncthreads();

    // ---- phase 3: layer-2 dense for these 16 nodes ----
    const int wave = t >> 6;
    const int lane = t & 63;
    const int n16 = lane & 15;
    const int quad = lane >> 4;
    const int node = base + n16;

    bf16x8 hfrag[4];
    const unsigned short* hrow = Hl + n16 * LSTR + quad * 8;
#pragma unroll
    for (int ks = 0; ks < 4; ks++)
        hfrag[ks] = *(const bf16x8*)(hrow + ks * 32);

    f32x4 acc[4];
#pragma unroll
    for (int ct = 0; ct < 4; ct++) {
        const unsigned short* wrow = Wc2 + (size_t)(wave * 64 + ct * 16 + n16) * DIM + quad * 8;
        f32x4 a = {0.f, 0.f, 0.f, 0.f};
#pragma unroll
        for (int ks = 0; ks < 4; ks++)
            a = __builtin_amdgcn_mfma_f32_16x16x32_bf16(
                    *(const bf16x8*)(wrow + ks * 32), hfrag[ks], a, 0, 0, 0);
        acc[ct] = a;
    }

    {
        unsigned short* zout = (wave < 2 ? z2 : zi2);
        unsigned short* orow = zout + (size_t)node * DIM + (wave & 1) * 64 + quad * 4;
#pragma unroll
        for (int ct = 0; ct < 4; ct++) {
            uint2 pk;
            pk.x = (unsigned int)f2bf(acc[ct][0]) | ((unsigned int)f2bf(acc[ct][1]) << 16);
            pk.y = (unsigned int)f2bf(acc[ct][2]) | ((unsigned int)f2bf(acc[ct][3]) << 16);
            *(uint2*)(orow + ct * 16) = pk;
        }
    }

    if (wave < 2) {
        float ps = 0.f, pd = 0.f;
#pragma unroll
        for (int ct = 0; ct < 4; ct++) {
            float4 as = *(const float4*)(W_a2 + wave * 64 + ct * 16 + quad * 4);
            float4 ad = *(const float4*)(W_a2 + DIM + wave * 64 + ct * 16 + quad * 4);
            ps += acc[ct][0] * as.x + acc[ct][1] * as.y
                + acc[ct][2] * as.z + acc[ct][3] * as.w;
            pd += acc[ct][0] * ad.x + acc[ct][1] * ad.y
                + acc[ct][2] * ad.z + acc[ct][3] * ad.w;
        }
        ps += __shfl_xor(ps, 16); ps += __shfl_xor(ps, 32);
        pd += __shfl_xor(pd, 16); pd += __shfl_xor(pd, 32);
        if (lane < 16) {
            (wave == 0 ? t_src0 : t_src1)[node] = ps;
            (wave == 0 ? t_dst0 : t_dst1)[node] = pd;
        }
    }
}

// ---------------------------------------------------------------------------
// aggr2 (final): same as aggr v5, writes f32 output.
// ---------------------------------------------------------------------------
__global__ __launch_bounds__(256, 3) void aggr_final(
    const unsigned short* __restrict__ z,    // z2
    const unsigned short* __restrict__ zi,   // zi2
    const float* __restrict__ s_src0, const float* __restrict__ s_src1,
    const float* __restrict__ s_dst0, const float* __restrict__ s_dst1,
    const float* __restrict__ edge_d,
    const int* __restrict__ edge_src,
    const float* __restrict__ W_V,           // W_V2
    const float* __restrict__ W_a,           // W_a2
    float* __restrict__ out_f32)
{
    __shared__ float alpha_s[16][DEG];
    __shared__ int   src_s[16][DEG];

    const int t = threadIdx.x;
    const int base = blockIdx.x * 16;

    {
        int nl = t >> 4, j = t & 15;
        int node = base + nl;
        int e = node * DEG + j;
        int s = edge_src[e];
        float coef = W_V[0] * W_a[2 * DIM];
        float x = (s_src0[s] + s_src1[s]) + (s_dst0[node] + s_dst1[node])
                + edge_d[e] * coef;
        x = x > 0.f ? x : 0.01f * x;
        float m = x;
        m = fmaxf(m, __shfl_xor(m, 1));
        m = fmaxf(m, __shfl_xor(m, 2));
        m = fmaxf(m, __shfl_xor(m, 4));
        m = fmaxf(m, __shfl_xor(m, 8));
        float ex = __expf(x - m);
        float d = ex;
        d += __shfl_xor(d, 1); d += __shfl_xor(d, 2);
        d += __shfl_xor(d, 4); d += __shfl_xor(d, 8);
        alpha_s[nl][j] = ex / d;
        src_s[nl][j] = s;
    }
    __syncthreads();

    const int nl = t >> 4;
    const int node = base + nl;
    const int c8 = (t & 15) * 8;

    uint4 raw[DEG];
#pragma unroll
    for (int j = 0; j < DEG; j++)
        raw[j] = *(const uint4*)(z + (size_t)src_s[nl][j] * DIM + c8);
    uint4 zr = *(const uint4*)(zi + (size_t)node * DIM + c8);

    float acc[8] = {};
#pragma unroll
    for (int j = 0; j < DEG; j++) {
        float a = alpha_s[nl][j];
        acc[0] += a * bf2f((unsigned short)raw[j].x);
        acc[1] += a * bf2f((unsigned short)(raw[j].x >> 16));
        acc[2] += a * bf2f((unsigned short)raw[j].y);
        acc[3] += a * bf2f((unsigned short)(raw[j].y >> 16));
        acc[4] += a * bf2f((unsigned short)raw[j].z);
        acc[5] += a * bf2f((unsigned short)(raw[j].z >> 16));
        acc[6] += a * bf2f((unsigned short)raw[j].w);
        acc[7] += a * bf2f((unsigned short)(raw[j].w >> 16));
    }

    float* op = out_f32 + (size_t)node * DIM + c8;
    *(float4*)op = make_float4(
        fmaxf(bf2f((unsigned short)zr.x) + acc[0], 0.f),
        fmaxf(bf2f((unsigned short)(zr.x >> 16)) + acc[1], 0.f),
        fmaxf(bf2f((unsigned short)zr.y) + acc[2], 0.f),
        fmaxf(bf2f((unsigned short)(zr.y >> 16)) + acc[3], 0.f));
    *(float4*)(op + 4) = make_float4(
        fmaxf(bf2f((unsigned short)zr.z) + acc[4], 0.f),
        fmaxf(bf2f((unsigned short)(zr.z >> 16)) + acc[5], 0.f),
        fmaxf(bf2f((unsigned short)zr.w) + acc[6], 0.f),
        fmaxf(bf2f((unsigned short)(zr.w >> 16)) + acc[7], 0.f));
}

// ---------------------------------------------------------------------------
extern "C" void kernel_launch(void* const* d_in, const int* in_sizes, int n_in,
                              void* d_out, int out_size, void* d_ws, size_t ws_size,
                              hipStream_t stream) {
    const float* attr     = (const float*)d_in[0];
    const float* edge_d   = (const float*)d_in[1];
    const float* W_V1     = (const float*)d_in[2];
    const float* W_W1     = (const float*)d_in[3];
    const float* W_U1     = (const float*)d_in[4];
    const float* W_a1     = (const float*)d_in[5];
    const float* W_V2     = (const float*)d_in[6];
    const float* W_W2     = (const float*)d_in[7];
    const float* W_U2     = (const float*)d_in[8];
    const float* W_a2     = (const float*)d_in[9];
    const int*   edge_src = (const int*)d_in[10];

    float* out = (float*)d_out;

    char* ws = (char*)d_ws;
    unsigned short* z1  = (unsigned short*)ws;                         // 25.6 MB
    unsigned short* zi1 = (unsigned short*)(ws + 26u * 1024 * 1024);
    unsigned short* z2  = (unsigned short*)(ws + 52u * 1024 * 1024);
    unsigned short* zi2 = (unsigned short*)(ws + 78u * 1024 * 1024);
    unsigned short* Wc1 = (unsigned short*)(ws + 104u * 1024 * 1024);  // 64 KB
    unsigned short* Wc2 = (unsigned short*)(ws + 105u * 1024 * 1024);  // 64 KB
    float* s_src0       = (float*)(ws + 106u * 1024 * 1024);
    float* s_src1       = (float*)(ws + 107u * 1024 * 1024);
    float* s_dst0       = (float*)(ws + 108u * 1024 * 1024);
    float* s_dst1       = (float*)(ws + 109u * 1024 * 1024);
    float* t_src0       = (float*)(ws + 110u * 1024 * 1024);
    float* t_src1       = (float*)(ws + 111u * 1024 * 1024);
    float* t_dst0       = (float*)(ws + 112u * 1024 * 1024);
    float* t_dst1       = (float*)(ws + 113u * 1024 * 1024);

    prep_w<<<256, 256, 0, stream>>>(W_W1, W_U1, W_W2, W_U2, Wc1, Wc2);

    dense_tile<<<DGRID, 256, 0, stream>>>(attr, Wc1, W_a1, z1, zi1,
                                          s_src0, s_src1, s_dst0, s_dst1);

    aggr_dense<<<6250, 256, 0, stream>>>(z1, zi1, s_src0, s_src1, s_dst0, s_dst1,
                                         edge_d, edge_src, W_V1, W_a1,
                                         Wc2, W_a2, z2, zi2,
                                         t_src0, t_src1, t_dst0, t_dst1);

    aggr_final<<<6250, 256, 0, stream>>>(z2, zi2, t_src0, t_src1, t_dst0, t_dst1,
                                         edge_d, edge_src, W_V2, W_a2, out);
}